// Round 1
// baseline (155.510 us; speedup 1.0000x reference)
//
#include <hip/hip_runtime.h>

#define N_TOK 2048
#define IN_FEAT 2048
#define NNZB 1228

typedef __attribute__((ext_vector_type(8))) short short8;
typedef __attribute__((ext_vector_type(4))) float floatx4;

__device__ __forceinline__ short f2bf(float f) {
  unsigned u = __builtin_bit_cast(unsigned, f);
  u += 0x7FFFu + ((u >> 16) & 1u);   // round-to-nearest-even
  return (short)(u >> 16);
}

__device__ __forceinline__ short8 cvt8(const float4 a, const float4 b) {
  short8 r;
  r[0] = f2bf(a.x); r[1] = f2bf(a.y); r[2] = f2bf(a.z); r[3] = f2bf(a.w);
  r[4] = f2bf(b.x); r[5] = f2bf(b.y); r[6] = f2bf(b.z); r[7] = f2bf(b.w);
  return r;
}

// One workgroup: 256 tokens x 1 output block (32 cols).
// 4 waves; each wave owns 64 tokens (4 M-fragments of 16).
// grid.x = (2048/256) * 64 = 512; ob = blockIdx.x & 63 so that consecutive
// blocks (round-robin across XCDs) share the same token tile of X in L2.
__global__ __launch_bounds__(256) void bsl_kernel(
    const float* __restrict__ x, const float* __restrict__ w,
    const int* __restrict__ oi, const int* __restrict__ ii,
    float* __restrict__ y) {
  const int ob   = blockIdx.x & 63;
  const int tile = blockIdx.x >> 6;
  const int lane = threadIdx.x & 63;
  const int wave = threadIdx.x >> 6;
  const int row16 = lane & 15;
  const int kgrp  = lane >> 4;   // 0..3

  // nnz range for this output block (oi sorted ascending)
  int lo = 0, hi = NNZB;
  while (lo < hi) { int m = (lo + hi) >> 1; if (oi[m] < ob) lo = m + 1; else hi = m; }
  const int e0 = lo;
  hi = NNZB;
  while (lo < hi) { int m = (lo + hi) >> 1; if (oi[m] < ob + 1) lo = m + 1; else hi = m; }
  const int e1 = lo;

  const int tokBase = tile * 256 + wave * 64;

  floatx4 zero = {0.f, 0.f, 0.f, 0.f};
  floatx4 acc[4][2];
  #pragma unroll
  for (int m = 0; m < 4; ++m) { acc[m][0] = zero; acc[m][1] = zero; }

  // lane-invariant part of the x address: token row (tokBase+row16), col group kgrp*8
  const float* xrow = x + (size_t)(tokBase + row16) * IN_FEAT + kgrp * 8;

  #pragma unroll 2
  for (int k = e0; k < e1; ++k) {
    const int ib = ii[k];
    // B fragments: B[kk][o] = w[o][kk]; lane reads w row (row16 / row16+16),
    // cols kgrp*8..+7 -> 8 contiguous floats
    const float* wb = w + (size_t)k * 1024 + kgrp * 8;
    const float4* wp0 = (const float4*)(wb + row16 * 32);
    const float4* wp1 = (const float4*)(wb + (row16 + 16) * 32);
    short8 bf0 = cvt8(wp0[0], wp0[1]);
    short8 bf1 = cvt8(wp1[0], wp1[1]);

    const float* xp = xrow + ib * 32;
    #pragma unroll
    for (int m = 0; m < 4; ++m) {
      const float4* ap = (const float4*)(xp + (size_t)(m * 16) * IN_FEAT);
      short8 af = cvt8(ap[0], ap[1]);
      acc[m][0] = __builtin_amdgcn_mfma_f32_16x16x32_bf16(af, bf0, acc[m][0], 0, 0, 0);
      acc[m][1] = __builtin_amdgcn_mfma_f32_16x16x32_bf16(af, bf1, acc[m][1], 0, 0, 0);
    }
  }

  // C/D layout (verified): col = lane&15, row = (lane>>4)*4 + reg
  #pragma unroll
  for (int m = 0; m < 4; ++m) {
    #pragma unroll
    for (int nf = 0; nf < 2; ++nf) {
      #pragma unroll
      for (int r = 0; r < 4; ++r) {
        const int row = tokBase + m * 16 + kgrp * 4 + r;
        const int col = ob * 32 + nf * 16 + row16;
        y[(size_t)row * 2048 + col] = acc[m][nf][r];
      }
    }
  }
}

extern "C" void kernel_launch(void* const* d_in, const int* in_sizes, int n_in,
                              void* d_out, int out_size, void* d_ws, size_t ws_size,
                              hipStream_t stream) {
  const float* x  = (const float*)d_in[0];
  const float* w  = (const float*)d_in[1];
  const int*   oi = (const int*)d_in[2];
  const int*   ii = (const int*)d_in[3];
  float* y = (float*)d_out;
  bsl_kernel<<<dim3(512), dim3(256), 0, stream>>>(x, w, oi, ii, y);
}

// Round 7
// 107.119 us; speedup vs baseline: 1.4517x; 1.4517x over previous
//
#include <hip/hip_runtime.h>

#define N_TOK 2048
#define IN_FEAT 2048
#define NNZB 1228
#define XN8 ((N_TOK * IN_FEAT) / 8)   // x elements / 8
#define WN8 ((NNZB * 1024) / 8)       // w elements / 8

typedef __attribute__((ext_vector_type(8))) short short8;
typedef __attribute__((ext_vector_type(4))) float floatx4;

__device__ __forceinline__ short f2bf(float f) {
  unsigned u = __builtin_bit_cast(unsigned, f);
  u += 0x7FFFu + ((u >> 16) & 1u);   // round-to-nearest-even
  return (short)(u >> 16);
}

__device__ __forceinline__ short8 cvt8(const float4 a, const float4 b) {
  short8 r;
  r[0] = f2bf(a.x); r[1] = f2bf(a.y); r[2] = f2bf(a.z); r[3] = f2bf(a.w);
  r[4] = f2bf(b.x); r[5] = f2bf(b.y); r[6] = f2bf(b.z); r[7] = f2bf(b.w);
  return r;
}

// One-shot f32 -> bf16 conversion of x and w into workspace.
__global__ __launch_bounds__(256) void cvt_kernel(
    const float* __restrict__ x, const float* __restrict__ w,
    short8* __restrict__ xb, short8* __restrict__ wb) {
  const int tid = blockIdx.x * 256 + threadIdx.x;
  if (tid < XN8) {
    const float4* p = (const float4*)x + (size_t)tid * 2;
    xb[tid] = cvt8(p[0], p[1]);
  } else if (tid < XN8 + WN8) {
    const int t = tid - XN8;
    const float4* p = (const float4*)w + (size_t)t * 2;
    wb[t] = cvt8(p[0], p[1]);
  }
}

// wg = 64 tokens x 1 output block (32 cols). 4 waves split the nnz range,
// partials tree-reduced through LDS. grid = ob*32 + tile (ob-outer) so each
// XCD's resident wgs share 4 X-tiles (1 MB) + all of W (2.45 MB) in its L2.
template <int USE_WS>
__global__ __launch_bounds__(256, 8) void bsl_main(
    const short8* __restrict__ xb, const short8* __restrict__ wb,
    const float* __restrict__ x, const float* __restrict__ w,
    const int* __restrict__ oi, const int* __restrict__ ii,
    float* __restrict__ y) {
  const int ob   = blockIdx.x >> 5;
  const int tile = blockIdx.x & 31;
  const int lane = threadIdx.x & 63;
  const int wave = threadIdx.x >> 6;
  const int row16 = lane & 15;
  const int kgrp  = lane >> 4;   // 0..3

  __shared__ float red[2][64 * 32];

  // nnz range for this output block (oi sorted ascending)
  int lo = 0, hi = NNZB;
  while (lo < hi) { int m = (lo + hi) >> 1; if (oi[m] < ob) lo = m + 1; else hi = m; }
  const int e0 = lo;
  hi = NNZB;
  while (lo < hi) { int m = (lo + hi) >> 1; if (oi[m] < ob + 1) lo = m + 1; else hi = m; }
  const int e1 = lo;
  const int cnt = e1 - e0;
  const int ks = e0 + (cnt * wave) / 4;
  const int ke = e0 + (cnt * (wave + 1)) / 4;

  const int tokBase = tile * 64;

  floatx4 acc[4][2] = {};

  if (USE_WS) {
    // bf16 path: xb rows are 256 short8s wide
    const short8* xrow = xb + (size_t)(tokBase + row16) * 256 + kgrp;
    #pragma unroll 2
    for (int k = ks; k < ke; ++k) {
      const int ib = ii[k];
      short8 b0 = wb[(size_t)k * 128 + row16 * 4 + kgrp];
      short8 b1 = wb[(size_t)k * 128 + (row16 + 16) * 4 + kgrp];
      const short8* xp = xrow + ib * 4;
      #pragma unroll
      for (int m = 0; m < 4; ++m) {
        short8 a = xp[m * 16 * 256];
        acc[m][0] = __builtin_amdgcn_mfma_f32_16x16x32_bf16(a, b0, acc[m][0], 0, 0, 0);
        acc[m][1] = __builtin_amdgcn_mfma_f32_16x16x32_bf16(a, b1, acc[m][1], 0, 0, 0);
      }
    }
  } else {
    // f32 fallback (workspace too small): convert inline
    const float* xrow = x + (size_t)(tokBase + row16) * IN_FEAT + kgrp * 8;
    #pragma unroll 2
    for (int k = ks; k < ke; ++k) {
      const int ib = ii[k];
      const float* wbp = w + (size_t)k * 1024 + kgrp * 8;
      const float4* wp0 = (const float4*)(wbp + row16 * 32);
      const float4* wp1 = (const float4*)(wbp + (row16 + 16) * 32);
      short8 b0 = cvt8(wp0[0], wp0[1]);
      short8 b1 = cvt8(wp1[0], wp1[1]);
      const float* xp = xrow + ib * 32;
      #pragma unroll
      for (int m = 0; m < 4; ++m) {
        const float4* ap = (const float4*)(xp + (size_t)(m * 16) * IN_FEAT);
        short8 a = cvt8(ap[0], ap[1]);
        acc[m][0] = __builtin_amdgcn_mfma_f32_16x16x32_bf16(a, b0, acc[m][0], 0, 0, 0);
        acc[m][1] = __builtin_amdgcn_mfma_f32_16x16x32_bf16(a, b1, acc[m][1], 0, 0, 0);
      }
    }
  }

  // tree reduce: (1->0, 3->2) then (2->0); wave 0 writes out.
  // acc[m][nf][r] -> LDS idx (m*16 + kgrp*4 + r)*32 + nf*16 + row16
  {
    float* b0p = red[0];
    float* b1p = red[1];
    if (wave == 1 || wave == 3) {
      float* b = (wave == 1) ? b0p : b1p;
      #pragma unroll
      for (int m = 0; m < 4; ++m)
        #pragma unroll
        for (int nf = 0; nf < 2; ++nf)
          #pragma unroll
          for (int r = 0; r < 4; ++r)
            b[(m * 16 + kgrp * 4 + r) * 32 + nf * 16 + row16] = acc[m][nf][r];
    }
    __syncthreads();
    if (wave == 0 || wave == 2) {
      const float* b = (wave == 0) ? b0p : b1p;
      #pragma unroll
      for (int m = 0; m < 4; ++m)
        #pragma unroll
        for (int nf = 0; nf < 2; ++nf)
          #pragma unroll
          for (int r = 0; r < 4; ++r)
            acc[m][nf][r] += b[(m * 16 + kgrp * 4 + r) * 32 + nf * 16 + row16];
    }
    __syncthreads();
    if (wave == 2) {
      #pragma unroll
      for (int m = 0; m < 4; ++m)
        #pragma unroll
        for (int nf = 0; nf < 2; ++nf)
          #pragma unroll
          for (int r = 0; r < 4; ++r)
            b0p[(m * 16 + kgrp * 4 + r) * 32 + nf * 16 + row16] = acc[m][nf][r];
    }
    __syncthreads();
    if (wave == 0) {
      #pragma unroll
      for (int m = 0; m < 4; ++m)
        #pragma unroll
        for (int nf = 0; nf < 2; ++nf)
          #pragma unroll
          for (int r = 0; r < 4; ++r) {
            float v = acc[m][nf][r] + b0p[(m * 16 + kgrp * 4 + r) * 32 + nf * 16 + row16];
            const int row = tokBase + m * 16 + kgrp * 4 + r;
            const int col = ob * 32 + nf * 16 + row16;
            y[(size_t)row * 2048 + col] = v;
          }
    }
  }
}

extern "C" void kernel_launch(void* const* d_in, const int* in_sizes, int n_in,
                              void* d_out, int out_size, void* d_ws, size_t ws_size,
                              hipStream_t stream) {
  const float* x  = (const float*)d_in[0];
  const float* w  = (const float*)d_in[1];
  const int*   oi = (const int*)d_in[2];
  const int*   ii = (const int*)d_in[3];
  float* y = (float*)d_out;

  const size_t need = (size_t)(XN8 + WN8) * 16;  // bytes of bf16 staging
  if (ws_size >= need) {
    short8* xb = (short8*)d_ws;
    short8* wb = xb + XN8;
    cvt_kernel<<<dim3((XN8 + WN8 + 255) / 256), dim3(256), 0, stream>>>(x, w, xb, wb);
    bsl_main<1><<<dim3(2048), dim3(256), 0, stream>>>(xb, wb, x, w, oi, ii, y);
  } else {
    bsl_main<0><<<dim3(2048), dim3(256), 0, stream>>>(nullptr, nullptr, x, w, oi, ii, y);
  }
}

// Round 10
// 105.561 us; speedup vs baseline: 1.4732x; 1.0148x over previous
//
#include <hip/hip_runtime.h>

#define N_TOK 2048
#define IN_FEAT 2048
#define NNZB 1228
#define XN8 ((N_TOK * IN_FEAT) / 8)   // x elements / 8
#define WN8 ((NNZB * 1024) / 8)       // w elements / 8

typedef __attribute__((ext_vector_type(8))) short short8;
typedef __attribute__((ext_vector_type(4))) float floatx4;

__device__ __forceinline__ short f2bf(float f) {
  unsigned u = __builtin_bit_cast(unsigned, f);
  u += 0x7FFFu + ((u >> 16) & 1u);   // round-to-nearest-even
  return (short)(u >> 16);
}

__device__ __forceinline__ short8 cvt8(const float4 a, const float4 b) {
  short8 r;
  r[0] = f2bf(a.x); r[1] = f2bf(a.y); r[2] = f2bf(a.z); r[3] = f2bf(a.w);
  r[4] = f2bf(b.x); r[5] = f2bf(b.y); r[6] = f2bf(b.z); r[7] = f2bf(b.w);
  return r;
}

// One-shot f32 -> bf16 conversion of x and w into workspace; block 0 also
// precomputes per-output-block nnz range offsets (oi is sorted).
__global__ __launch_bounds__(256) void cvt_kernel(
    const float* __restrict__ x, const float* __restrict__ w,
    const int* __restrict__ oi,
    short8* __restrict__ xb, short8* __restrict__ wb, int* __restrict__ offs) {
  const int tid = blockIdx.x * 256 + threadIdx.x;
  if (blockIdx.x == 0 && threadIdx.x < 65) {
    const int target = threadIdx.x;
    int lo = 0, hi = NNZB;
    while (lo < hi) { int m = (lo + hi) >> 1; if (oi[m] < target) lo = m + 1; else hi = m; }
    offs[threadIdx.x] = lo;
  }
  if (tid < XN8) {
    const float4* p = (const float4*)x + (size_t)tid * 2;
    xb[tid] = cvt8(p[0], p[1]);
  } else if (tid < XN8 + WN8) {
    const int t = tid - XN8;
    const float4* p = (const float4*)w + (size_t)t * 2;
    wb[t] = cvt8(p[0], p[1]);
  }
}

// wg = 64 tokens x 1 output block (32 cols). 4 waves split the nnz range,
// partials tree-reduced through LDS. grid = ob*32 + tile (ob-outer) so each
// XCD's resident wgs share 4 X-tiles (1 MB) + all of W (2.45 MB) in its L2.
// launch_bounds (256,4): <=128 VGPR, no spills (acc=32 + frags + addrs ~70-90).
template <int USE_WS>
__global__ __launch_bounds__(256, 4) void bsl_main(
    const short8* __restrict__ xb, const short8* __restrict__ wb,
    const int* __restrict__ offs,
    const float* __restrict__ x, const float* __restrict__ w,
    const int* __restrict__ oi, const int* __restrict__ ii,
    float* __restrict__ y) {
  const int ob   = blockIdx.x >> 5;
  const int tile = blockIdx.x & 31;
  const int lane = threadIdx.x & 63;
  // scalarize the wave index: makes ks/ke/k SGPR -> ii[k] becomes s_load
  const int wv   = __builtin_amdgcn_readfirstlane(threadIdx.x >> 6);
  const int row16 = lane & 15;
  const int kgrp  = lane >> 4;   // 0..3

  __shared__ float red[2][64 * 32];

  int e0, e1;
  if (USE_WS) {
    e0 = offs[ob];
    e1 = offs[ob + 1];
  } else {
    int lo = 0, hi = NNZB;
    while (lo < hi) { int m = (lo + hi) >> 1; if (oi[m] < ob) lo = m + 1; else hi = m; }
    e0 = lo;
    hi = NNZB;
    while (lo < hi) { int m = (lo + hi) >> 1; if (oi[m] < ob + 1) lo = m + 1; else hi = m; }
    e1 = lo;
  }
  const int cnt = e1 - e0;
  const int ks = e0 + (cnt * wv) / 4;
  const int ke = e0 + (cnt * (wv + 1)) / 4;

  const int tokBase = tile * 64;

  floatx4 acc[4][2] = {};

  if (USE_WS) {
    // bf16 path: xb rows are 256 short8s wide
    const short8* xrow = xb + (size_t)(tokBase + row16) * 256 + kgrp;
    #pragma unroll 2
    for (int k = ks; k < ke; ++k) {
      const int ib = ii[k];
      short8 b0 = wb[(size_t)k * 128 + row16 * 4 + kgrp];
      short8 b1 = wb[(size_t)k * 128 + (row16 + 16) * 4 + kgrp];
      const short8* xp = xrow + ib * 4;
      #pragma unroll
      for (int m = 0; m < 4; ++m) {
        short8 a = xp[m * 16 * 256];
        acc[m][0] = __builtin_amdgcn_mfma_f32_16x16x32_bf16(a, b0, acc[m][0], 0, 0, 0);
        acc[m][1] = __builtin_amdgcn_mfma_f32_16x16x32_bf16(a, b1, acc[m][1], 0, 0, 0);
      }
    }
  } else {
    // f32 fallback (workspace too small): convert inline
    const float* xrow = x + (size_t)(tokBase + row16) * IN_FEAT + kgrp * 8;
    #pragma unroll 2
    for (int k = ks; k < ke; ++k) {
      const int ib = ii[k];
      const float* wbp = w + (size_t)k * 1024 + kgrp * 8;
      const float4* wp0 = (const float4*)(wbp + row16 * 32);
      const float4* wp1 = (const float4*)(wbp + (row16 + 16) * 32);
      short8 b0 = cvt8(wp0[0], wp0[1]);
      short8 b1 = cvt8(wp1[0], wp1[1]);
      const float* xp = xrow + ib * 32;
      #pragma unroll
      for (int m = 0; m < 4; ++m) {
        const float4* ap = (const float4*)(xp + (size_t)(m * 16) * IN_FEAT);
        short8 a = cvt8(ap[0], ap[1]);
        acc[m][0] = __builtin_amdgcn_mfma_f32_16x16x32_bf16(a, b0, acc[m][0], 0, 0, 0);
        acc[m][1] = __builtin_amdgcn_mfma_f32_16x16x32_bf16(a, b1, acc[m][1], 0, 0, 0);
      }
    }
  }

  // tree reduce: (1->0, 3->2) then (2->0); wave 0 writes out.
  // acc[m][nf][r] -> LDS idx (m*16 + kgrp*4 + r)*32 + nf*16 + row16
  {
    float* b0p = red[0];
    float* b1p = red[1];
    if (wv == 1 || wv == 3) {
      float* b = (wv == 1) ? b0p : b1p;
      #pragma unroll
      for (int m = 0; m < 4; ++m)
        #pragma unroll
        for (int nf = 0; nf < 2; ++nf)
          #pragma unroll
          for (int r = 0; r < 4; ++r)
            b[(m * 16 + kgrp * 4 + r) * 32 + nf * 16 + row16] = acc[m][nf][r];
    }
    __syncthreads();
    if (wv == 0 || wv == 2) {
      const float* b = (wv == 0) ? b0p : b1p;
      #pragma unroll
      for (int m = 0; m < 4; ++m)
        #pragma unroll
        for (int nf = 0; nf < 2; ++nf)
          #pragma unroll
          for (int r = 0; r < 4; ++r)
            acc[m][nf][r] += b[(m * 16 + kgrp * 4 + r) * 32 + nf * 16 + row16];
    }
    __syncthreads();
    if (wv == 2) {
      #pragma unroll
      for (int m = 0; m < 4; ++m)
        #pragma unroll
        for (int nf = 0; nf < 2; ++nf)
          #pragma unroll
          for (int r = 0; r < 4; ++r)
            b0p[(m * 16 + kgrp * 4 + r) * 32 + nf * 16 + row16] = acc[m][nf][r];
    }
    __syncthreads();
    if (wv == 0) {
      #pragma unroll
      for (int m = 0; m < 4; ++m)
        #pragma unroll
        for (int nf = 0; nf < 2; ++nf)
          #pragma unroll
          for (int r = 0; r < 4; ++r) {
            float v = acc[m][nf][r] + b0p[(m * 16 + kgrp * 4 + r) * 32 + nf * 16 + row16];
            const int row = tokBase + m * 16 + kgrp * 4 + r;
            const int col = ob * 32 + nf * 16 + row16;
            y[(size_t)row * 2048 + col] = v;
          }
    }
  }
}

extern "C" void kernel_launch(void* const* d_in, const int* in_sizes, int n_in,
                              void* d_out, int out_size, void* d_ws, size_t ws_size,
                              hipStream_t stream) {
  const float* x  = (const float*)d_in[0];
  const float* w  = (const float*)d_in[1];
  const int*   oi = (const int*)d_in[2];
  const int*   ii = (const int*)d_in[3];
  float* y = (float*)d_out;

  const size_t need = (size_t)(XN8 + WN8) * 16 + 65 * sizeof(int);
  if (ws_size >= need) {
    short8* xb = (short8*)d_ws;
    short8* wb = xb + XN8;
    int* offs = (int*)(wb + WN8);
    cvt_kernel<<<dim3((XN8 + WN8 + 255) / 256), dim3(256), 0, stream>>>(x, w, oi, xb, wb, offs);
    bsl_main<1><<<dim3(2048), dim3(256), 0, stream>>>(xb, wb, offs, x, w, oi, ii, y);
  } else {
    bsl_main<0><<<dim3(2048), dim3(256), 0, stream>>>(nullptr, nullptr, nullptr, x, w, oi, ii, y);
  }
}